// Round 1
// baseline (68.732 us; speedup 1.0000x reference)
//
#include <hip/hip_runtime.h>

// ToroidalSOM distance kernel: out[b][n] = ||w_n - x_b||^2
//   = ||w_n||^2 + ||x_b||^2 - 2 * dot(w_n, x_b)
// B=128, D=64, N=R*C=16384. fp32 throughout.
//
// Mapping: 1 thread = 1 neuron (w_n held in 64 VGPRs), 16 batches per block.
// Grid (64, 8) = 512 blocks -> 2 blocks/CU, 2 waves/SIMD.
// x batch-tile (16x64 fp32 = 4 KB) staged in LDS; inner-loop x reads are
// wave-uniform -> LDS broadcast (conflict-free).

#define SOM_B   128
#define SOM_D   64
#define SOM_N   16384   // 128*128 neurons
#define SOM_BT  16      // batches per block
#define SOM_TPB 256

__global__ __launch_bounds__(SOM_TPB, 2)
void som_dist_kernel(const float* __restrict__ x,
                     const float* __restrict__ w,
                     float* __restrict__ out) {
    __shared__ float xs[SOM_BT][SOM_D];   // 4 KB
    __shared__ float x2s[SOM_BT];         // per-batch ||x||^2

    const int tid = threadIdx.x;
    const int n   = blockIdx.x * SOM_TPB + tid;   // neuron index
    const int b0  = blockIdx.y * SOM_BT;          // first batch of this tile

    // Cooperative x-tile load: SOM_BT*SOM_D = 1024 floats = 256 float4s,
    // exactly one float4 per thread (coalesced).
    {
        const float4* xg = (const float4*)(x + (size_t)b0 * SOM_D);
        ((float4*)&xs[0][0])[tid] = xg[tid];
    }
    __syncthreads();

    // Per-batch ||x||^2 (16 threads, trivial work)
    if (tid < SOM_BT) {
        float s = 0.f;
        #pragma unroll
        for (int d = 0; d < SOM_D; ++d) {
            float v = xs[tid][d];
            s += v * v;
        }
        x2s[tid] = s;
    }

    // Load this neuron's weight vector into registers (16 x float4 = 64 VGPRs)
    float4 wr[16];
    {
        const float4* wg = (const float4*)(w + (size_t)n * SOM_D);
        #pragma unroll
        for (int i = 0; i < 16; ++i) wr[i] = wg[i];
    }
    float wn2 = 0.f;
    #pragma unroll
    for (int i = 0; i < 16; ++i) {
        wn2 += wr[i].x * wr[i].x + wr[i].y * wr[i].y
             + wr[i].z * wr[i].z + wr[i].w * wr[i].w;
    }

    __syncthreads();  // x2s visible to all threads

    #pragma unroll
    for (int b = 0; b < SOM_BT; ++b) {
        const float4* xrow = (const float4*)&xs[b][0];
        float acc = 0.f;
        #pragma unroll
        for (int i = 0; i < 16; ++i) {
            float4 xv = xrow[i];   // wave-uniform -> LDS broadcast
            acc += wr[i].x * xv.x + wr[i].y * xv.y
                 + wr[i].z * xv.z + wr[i].w * xv.w;
        }
        float res = wn2 + x2s[b] - 2.f * acc;
        out[(size_t)(b0 + b) * SOM_N + n] = res;   // coalesced store
    }
}

extern "C" void kernel_launch(void* const* d_in, const int* in_sizes, int n_in,
                              void* d_out, int out_size, void* d_ws, size_t ws_size,
                              hipStream_t stream) {
    const float* x = (const float*)d_in[0];   // (128, 64)
    const float* w = (const float*)d_in[1];   // (128, 128, 64)
    float* out = (float*)d_out;               // (128, 128, 128)

    dim3 grid(SOM_N / SOM_TPB, SOM_B / SOM_BT);   // (64, 8)
    dim3 block(SOM_TPB);
    som_dist_kernel<<<grid, block, 0, stream>>>(x, w, out);
}